// Round 6
// baseline (575.242 us; speedup 1.0000x reference)
//
#include <hip/hip_runtime.h>
#include <float.h>

#define NN 5000
#define NE 50000
#define C 64
#define CHW4 768       // float4 units per node row
#define MAXD 64

typedef float f32x4 __attribute__((ext_vector_type(4)));
typedef unsigned int u32x2 __attribute__((ext_vector_type(2)));
typedef unsigned int u32x4 __attribute__((ext_vector_type(4)));

#if defined(__has_builtin)
#if __has_builtin(__builtin_amdgcn_make_buffer_rsrc) && \
    __has_builtin(__builtin_amdgcn_raw_buffer_load_b64) && \
    __has_builtin(__builtin_amdgcn_raw_buffer_load_b128) && \
    __has_builtin(__builtin_amdgcn_raw_buffer_store_b64)
#define USE_BUF 1
#endif
#endif

#define STREAM_AUX 19  // SC0(1) | NT(2) | SC1(16): system-scope non-temporal

__device__ __forceinline__ unsigned int pack_bf16(float a, float b) {
  unsigned int ua = __float_as_uint(a), ub = __float_as_uint(b);
  ua = (ua + 0x7FFFu + ((ua >> 16) & 1u)) >> 16;
  ub = (ub + 0x7FFFu + ((ub >> 16) & 1u)) & 0xFFFF0000u;
  return ua | ub;
}
__device__ __forceinline__ float bf_lo(unsigned int u) { return __uint_as_float(u << 16); }
__device__ __forceinline__ float bf_hi(unsigned int u) { return __uint_as_float(u & 0xFFFF0000u); }

// ---------------- CSR build ----------------
__global__ void hist_kernel(const int* __restrict__ dst, int* __restrict__ cnt) {
  int e = blockIdx.x * 256 + threadIdx.x;
  if (e < NE) atomicAdd(&cnt[dst[e]], 1);
}

__global__ void scan_kernel(const int* __restrict__ cnt, int* __restrict__ off, int* __restrict__ cur) {
  __shared__ int tsum[256];
  int t = threadIdx.x;
  constexpr int PER = 20;
  int base = t * PER;
  int vals[PER];
  int local = 0;
#pragma unroll
  for (int i = 0; i < PER; i++) {
    int idx = base + i;
    int v = (idx < NN) ? cnt[idx] : 0;
    vals[i] = local;
    local += v;
  }
  tsum[t] = local;
  __syncthreads();
  for (int o = 1; o < 256; o <<= 1) {
    int v = (t >= o) ? tsum[t - o] : 0;
    __syncthreads();
    tsum[t] += v;
    __syncthreads();
  }
  int excl = (t == 0) ? 0 : tsum[t - 1];
#pragma unroll
  for (int i = 0; i < PER; i++) {
    int idx = base + i;
    if (idx < NN) {
      int o2 = excl + vals[i];
      off[idx] = o2;
      cur[idx] = o2;
    }
  }
  if (t == 255) off[NN] = excl + local;
}

__global__ void scatter_kernel(const int* __restrict__ dst, const int* __restrict__ src,
                               int* __restrict__ cur, int* __restrict__ eids, int* __restrict__ srcs) {
  int e = blockIdx.x * 256 + threadIdx.x;
  if (e < NE) {
    int p = atomicAdd(&cur[dst[e]], 1);
    eids[p] = e;
    srcs[p] = src[e];
  }
}

// ---------------- init: node_feats -> bf16 mirror + layer-0 BN stats ----------------
__global__ __launch_bounds__(256) void init_kernel(const float* __restrict__ hv,
                                                   u32x2* __restrict__ hvb,
                                                   float* __restrict__ statsN) {
  __shared__ float bsum[64], bsq[64];
  int n = blockIdx.x, t = threadIdx.x;
  if (t < 64) {
    bsum[t] = 0.f;
    bsq[t] = 0.f;
  }
  __syncthreads();
  const float4* hv4 = (const float4*)hv;
#pragma unroll
  for (int j = 0; j < 3; j++) {
    int q = t + j * 256;
    int c = q / 12;
    float4 v = hv4[(size_t)n * CHW4 + q];
    u32x2 o;
    o.x = pack_bf16(v.x, v.y);
    o.y = pack_bf16(v.z, v.w);
    hvb[(size_t)n * CHW4 + q] = o;
    atomicAdd(&bsum[c], v.x + v.y + v.z + v.w);
    atomicAdd(&bsq[c], v.x * v.x + v.y * v.y + v.z * v.z + v.w * v.w);
  }
  __syncthreads();
  int r = n & 7;
  if (t < 64) atomicAdd(&statsN[r * 128 + t], bsum[t]);
  else if (t < 128) atomicAdd(&statsN[r * 128 + 64 + (t - 64)], bsq[t - 64]);
}

__global__ void finalize2_kernel(const float* __restrict__ statsN, const float* __restrict__ gamma,
                                 const float* __restrict__ beta, float* __restrict__ sc,
                                 float* __restrict__ sh) {
  int c = threadIdx.x;
  if (c < C) {
    float s = 0.f, q = 0.f;
#pragma unroll
    for (int r = 0; r < 8; r++) {
      s += statsN[r * 128 + c];
      q += statsN[r * 128 + 64 + c];
    }
    const float inv = 1.f / 240000.f;
    float mu = s * inv;
    float var = q * inv - mu * mu;
    float scale = gamma[c] * rsqrtf(var + 1e-5f);
    sc[c] = scale;
    sh[c] = beta[c] - mu * scale;
  }
}

// ---------------- Fused GENConv layer ----------------
// One block per node. Gathers raw bf16 hv mirror + applies BN+ReLU inline;
// he streamed with system-scope non-temporal policy (no MALL pollution).
// Shift-free softmax (m bounded); 64x64 linear + residual + next BN stats.
template <bool FIRST, bool LAST>
__global__ __launch_bounds__(256) void aggregate_kernel(
    const float* __restrict__ hv, const float* __restrict__ he,
    const u32x2* __restrict__ hvbIn, u32x2* __restrict__ hvbOut,
    u32x2* __restrict__ heb,
    const int* __restrict__ srcs, const int* __restrict__ eids, const int* __restrict__ off,
    const float* __restrict__ Wg, const float* __restrict__ bg,
    const float* __restrict__ sc, const float* __restrict__ sh,
    float* __restrict__ hvNext, float* __restrict__ statsNext,
    const float* __restrict__ oW, const float* __restrict__ ob,
    float* __restrict__ out) {
  __shared__ float Wl[4096];
  __shared__ float fl[3072];
  __shared__ float scl[64], shl[64];
  __shared__ int sS[MAXD], sE[MAXD];
  __shared__ float bsum[64], bsq[64];

  int n = blockIdx.x, t = threadIdx.x;
  for (int i = t; i < 4096; i += 256) Wl[i] = Wg[i];
  if (t < 64) {
    scl[t] = sc[t];
    shl[t] = sh[t];
    bsum[t] = 0.f;
    bsq[t] = 0.f;
  }
  __syncthreads();

  const float4* hv4 = (const float4*)hv;
  const f32x4* heV = (const f32x4*)he;

#ifdef USE_BUF
  auto srdHe = __builtin_amdgcn_make_buffer_rsrc((void*)he, (short)0, NE * 12288, 0x00020000);
  auto srdHeb = __builtin_amdgcn_make_buffer_rsrc((void*)heb, (short)0, NE * 6144, 0x00020000);
#endif

  float scv[3], shv[3], h1[12];
#pragma unroll
  for (int j = 0; j < 3; j++) {
    int q = t + j * 256;
    int c = q / 12;
    scv[j] = scl[c];
    shv[j] = shl[c];
    float4 v = hv4[(size_t)n * CHW4 + q];
    h1[4 * j + 0] = fmaxf(v.x * scv[j] + shv[j], 0.f);
    h1[4 * j + 1] = fmaxf(v.y * scv[j] + shv[j], 0.f);
    h1[4 * j + 2] = fmaxf(v.z * scv[j] + shv[j], 0.f);
    h1[4 * j + 3] = fmaxf(v.w * scv[j] + shv[j], 0.f);
  }

  float S[12], T[12];
#pragma unroll
  for (int i = 0; i < 12; i++) {
    S[i] = 0.f;
    T[i] = 0.f;
  }

  int e0 = off[n], d = off[n + 1] - e0;
  for (int base = 0; base < d; base += MAXD) {
    int cnt = min(MAXD, d - base);
    __syncthreads();
    if (t < cnt) {
      sS[t] = srcs[e0 + base + t];
      if (FIRST) sE[t] = eids[e0 + base + t];
    }
    __syncthreads();
#pragma unroll 2
    for (int k = 0; k < cnt; k++) {
      size_t hb = (size_t)sS[k] * CHW4;
      int pbq = (e0 + base + k) * CHW4;  // CSR-slot base for heb
#pragma unroll
      for (int j = 0; j < 3; j++) {
        int q = t + j * 256;
        u32x2 hg = hvbIn[hb + q];  // bf16 raw-hv gather (MALL-resident)
        float hgf[4];
        hgf[0] = fmaxf(bf_lo(hg.x) * scv[j] + shv[j], 0.f);
        hgf[1] = fmaxf(bf_hi(hg.x) * scv[j] + shv[j], 0.f);
        hgf[2] = fmaxf(bf_lo(hg.y) * scv[j] + shv[j], 0.f);
        hgf[3] = fmaxf(bf_hi(hg.y) * scv[j] + shv[j], 0.f);
        float hef[4];
        if (FIRST) {
          int ebq = sE[k] * CHW4 + q;
          f32x4 b;
#ifdef USE_BUF
          u32x4 raw = __builtin_amdgcn_raw_buffer_load_b128(srdHe, ebq * 16, 0, STREAM_AUX);
          b = __builtin_bit_cast(f32x4, raw);
#else
          b = __builtin_nontemporal_load(&heV[ebq]);
#endif
          hef[0] = b.x; hef[1] = b.y; hef[2] = b.z; hef[3] = b.w;
          u32x2 o;
          o.x = pack_bf16(b.x, b.y);
          o.y = pack_bf16(b.z, b.w);
#ifdef USE_BUF
          __builtin_amdgcn_raw_buffer_store_b64(o, srdHeb, (pbq + q) * 8, 0, STREAM_AUX);
#else
          __builtin_nontemporal_store(o, &heb[pbq + q]);
#endif
        } else {
          u32x2 bb;
#ifdef USE_BUF
          bb = __builtin_amdgcn_raw_buffer_load_b64(srdHeb, (pbq + q) * 8, 0, STREAM_AUX);
#else
          bb = __builtin_nontemporal_load(&heb[pbq + q]);
#endif
          hef[0] = bf_lo(bb.x); hef[1] = bf_hi(bb.x); hef[2] = bf_lo(bb.y); hef[3] = bf_hi(bb.y);
        }
#pragma unroll
        for (int u = 0; u < 4; u++) {
          float m = fmaxf(hgf[u] + hef[u], 0.f) + 1e-7f;
          float e = __expf(m);  // shift-free softmax: m bounded, no overflow
          int idx = j * 4 + u;
          S[idx] += e;
          T[idx] += e * m;
        }
      }
    }
  }

  bool hasE = d > 0;
  float4* fl4 = (float4*)fl;
#pragma unroll
  for (int j = 0; j < 3; j++) {
    int q = t + j * 256, idx = 4 * j;
    float4 f;
    f.x = h1[idx + 0] + (hasE ? T[idx + 0] / S[idx + 0] : 0.f);
    f.y = h1[idx + 1] + (hasE ? T[idx + 1] / S[idx + 1] : 0.f);
    f.z = h1[idx + 2] + (hasE ? T[idx + 2] / S[idx + 2] : 0.f);
    f.w = h1[idx + 3] + (hasE ? T[idx + 3] / S[idx + 3] : 0.f);
    fl4[q] = f;
  }
  __syncthreads();

  // linear: 192 threads, each owns 4 consecutive out-channels x one h position
  int o0 = (t / 12) * 4, hbp = t % 12;
  float4 acc[4];
  if (t < 192) {
#pragma unroll
    for (int i = 0; i < 4; i++) {
      float bv = bg[o0 + i];
      acc[i] = make_float4(bv, bv, bv, bv);
    }
    const float4* w4 = (const float4*)Wl;
    int widx = o0 >> 2;
    for (int c2 = 0; c2 < 64; c2++) {
      float4 fv = fl4[c2 * 12 + hbp];
      float4 wv = w4[c2 * 16 + widx];
      acc[0].x += wv.x * fv.x; acc[0].y += wv.x * fv.y; acc[0].z += wv.x * fv.z; acc[0].w += wv.x * fv.w;
      acc[1].x += wv.y * fv.x; acc[1].y += wv.y * fv.y; acc[1].z += wv.y * fv.z; acc[1].w += wv.y * fv.w;
      acc[2].x += wv.z * fv.x; acc[2].y += wv.z * fv.y; acc[2].z += wv.z * fv.z; acc[2].w += wv.z * fv.w;
      acc[3].x += wv.w * fv.x; acc[3].y += wv.w * fv.y; acc[3].z += wv.w * fv.z; acc[3].w += wv.w * fv.w;
    }
#pragma unroll
    for (int i = 0; i < 4; i++) {
      float4 r = hv4[(size_t)n * CHW4 + (o0 + i) * 12 + hbp];
      acc[i].x += r.x; acc[i].y += r.y; acc[i].z += r.z; acc[i].w += r.w;
    }
  }

  if constexpr (!LAST) {
    if (t < 192) {
      float4* hn4 = (float4*)hvNext;
#pragma unroll
      for (int i = 0; i < 4; i++) {
        int pos = (o0 + i) * 12 + hbp;
        hn4[(size_t)n * CHW4 + pos] = acc[i];
        u32x2 ob2;
        ob2.x = pack_bf16(acc[i].x, acc[i].y);
        ob2.y = pack_bf16(acc[i].z, acc[i].w);
        hvbOut[(size_t)n * CHW4 + pos] = ob2;  // bf16 mirror for next layer's gathers
        float s4 = acc[i].x + acc[i].y + acc[i].z + acc[i].w;
        float q4 = acc[i].x * acc[i].x + acc[i].y * acc[i].y + acc[i].z * acc[i].z + acc[i].w * acc[i].w;
        atomicAdd(&bsum[o0 + i], s4);
        atomicAdd(&bsq[o0 + i], q4);
      }
    }
    __syncthreads();
    int r = n & 7;
    if (t < 64) atomicAdd(&statsNext[r * 128 + t], bsum[t]);
    else if (t < 128) atomicAdd(&statsNext[r * 128 + 64 + (t - 64)], bsq[t - 64]);
  } else {
    __syncthreads();
    if (t < 192) {
#pragma unroll
      for (int i = 0; i < 4; i++) fl4[(o0 + i) * 12 + hbp] = acc[i];
    }
    for (int i = t; i < 768; i += 256) Wl[i] = oW[i];
    __syncthreads();
    for (int i = t; i < 768; i += 256) {
      float4 v = fl4[i];
      Wl[1024 + i] = (v.x + v.y + v.z + v.w) * 0.25f;
    }
    __syncthreads();
    if (t < 144) {
      int o = t / 12, hb = t % 12;
      float bias = ob[o];
      float4 a = make_float4(bias, bias, bias, bias);
      for (int c2 = 0; c2 < 64; c2++) {
        float4 v = fl4[c2 * 12 + hb];
        float wv = Wl[c2 * 12 + o] * Wl[1024 + c2 * 12 + hb];
        a.x += wv * v.x; a.y += wv * v.y; a.z += wv * v.z; a.w += wv * v.w;
      }
      ((float4*)out)[(size_t)n * 144 + t] = a;
    }
  }
}

extern "C" void kernel_launch(void* const* d_in, const int* in_sizes, int n_in,
                              void* d_out, int out_size, void* d_ws, size_t ws_size,
                              hipStream_t stream) {
  const float* node_feats = (const float*)d_in[0];
  const float* edge_feats = (const float*)d_in[1];
  const int* src = (const int*)d_in[2];
  const int* dst = (const int*)d_in[3];
  const float* bn_gamma = (const float*)d_in[4];
  const float* bn_beta = (const float*)d_in[5];
  const float* gen_W = (const float*)d_in[6];
  const float* gen_b = (const float*)d_in[7];
  const float* out_W = (const float*)d_in[8];
  const float* out_b = (const float*)d_in[9];
  float* out = (float*)d_out;

  char* ws = (char*)d_ws;
  float* hvA = (float*)ws;                        // 61,440,000 B
  float* hvB = (float*)(ws + 61440000);           // 61,440,000 B
  u32x2* hvbA = (u32x2*)(ws + 122880000);         // 30,720,000 B (bf16 raw hv)
  u32x2* hvbB = (u32x2*)(ws + 153600000);         // 30,720,000 B
  u32x2* heb = (u32x2*)(ws + 184320000);          // 307,200,000 B (bf16 he, CSR order)
  float* statsN = (float*)(ws + 491520000);       // 4096 B
  float* sc = (float*)(ws + 491524096);           // 256 B
  float* sh = (float*)(ws + 491524352);           // 256 B
  int* cnt = (int*)(ws + 491524608);              // 20,000 B
  int* off = (int*)(ws + 491544608);              // 20,004 B
  int* cur = (int*)(ws + 491564612);              // 20,000 B
  int* eids = (int*)(ws + 491584612);             // 200,000 B
  int* srcs = (int*)(ws + 491784612);             // 200,000 B

  hipMemsetAsync(cnt, 0, NN * sizeof(int), stream);
  hist_kernel<<<(NE + 255) / 256, 256, 0, stream>>>(dst, cnt);
  scan_kernel<<<1, 256, 0, stream>>>(cnt, off, cur);
  scatter_kernel<<<(NE + 255) / 256, 256, 0, stream>>>(dst, src, cur, eids, srcs);

  hipMemsetAsync(statsN, 0, 1024 * sizeof(float), stream);
  init_kernel<<<NN, 256, 0, stream>>>(node_feats, hvbA, statsN);

  // layer 0
  finalize2_kernel<<<1, 64, 0, stream>>>(statsN, bn_gamma, bn_beta, sc, sh);
  hipMemsetAsync(statsN, 0, 1024 * sizeof(float), stream);
  aggregate_kernel<true, false><<<NN, 256, 0, stream>>>(
      node_feats, edge_feats, hvbA, hvbB, heb, srcs, eids, off, gen_W, gen_b,
      sc, sh, hvA, statsN, out_W, out_b, out);

  // layer 1
  finalize2_kernel<<<1, 64, 0, stream>>>(statsN, bn_gamma + C, bn_beta + C, sc, sh);
  hipMemsetAsync(statsN, 0, 1024 * sizeof(float), stream);
  aggregate_kernel<false, false><<<NN, 256, 0, stream>>>(
      hvA, edge_feats, hvbB, hvbA, heb, srcs, eids, off, gen_W + C * C, gen_b + C,
      sc, sh, hvB, statsN, out_W, out_b, out);

  // layer 2 (fused output)
  finalize2_kernel<<<1, 64, 0, stream>>>(statsN, bn_gamma + 2 * C, bn_beta + 2 * C, sc, sh);
  aggregate_kernel<false, true><<<NN, 256, 0, stream>>>(
      hvB, edge_feats, hvbA, hvbB, heb, srcs, eids, off, gen_W + 2 * C * C, gen_b + 2 * C,
      sc, sh, hvA, statsN, out_W, out_b, out);
}

// Round 7
// 573.293 us; speedup vs baseline: 1.0034x; 1.0034x over previous
//
#include <hip/hip_runtime.h>
#include <float.h>

#define NN 5000
#define NE 50000
#define C 64
#define CHW4 768       // float4 units per node row
#define MAXD 64

typedef float f32x4 __attribute__((ext_vector_type(4)));
typedef unsigned int u32x2 __attribute__((ext_vector_type(2)));

__device__ __forceinline__ unsigned int pack_bf16(float a, float b) {
  unsigned int ua = __float_as_uint(a), ub = __float_as_uint(b);
  ua = (ua + 0x7FFFu + ((ua >> 16) & 1u)) >> 16;
  ub = (ub + 0x7FFFu + ((ub >> 16) & 1u)) & 0xFFFF0000u;
  return ua | ub;
}
__device__ __forceinline__ float bf_lo(unsigned int u) { return __uint_as_float(u << 16); }
__device__ __forceinline__ float bf_hi(unsigned int u) { return __uint_as_float(u & 0xFFFF0000u); }

// ---------------- CSR build ----------------
__global__ void hist_kernel(const int* __restrict__ dst, int* __restrict__ cnt) {
  int e = blockIdx.x * 256 + threadIdx.x;
  if (e < NE) atomicAdd(&cnt[dst[e]], 1);
}

__global__ void scan_kernel(const int* __restrict__ cnt, int* __restrict__ off, int* __restrict__ cur) {
  __shared__ int tsum[256];
  int t = threadIdx.x;
  constexpr int PER = 20;
  int base = t * PER;
  int vals[PER];
  int local = 0;
#pragma unroll
  for (int i = 0; i < PER; i++) {
    int idx = base + i;
    int v = (idx < NN) ? cnt[idx] : 0;
    vals[i] = local;
    local += v;
  }
  tsum[t] = local;
  __syncthreads();
  for (int o = 1; o < 256; o <<= 1) {
    int v = (t >= o) ? tsum[t - o] : 0;
    __syncthreads();
    tsum[t] += v;
    __syncthreads();
  }
  int excl = (t == 0) ? 0 : tsum[t - 1];
#pragma unroll
  for (int i = 0; i < PER; i++) {
    int idx = base + i;
    if (idx < NN) {
      int o2 = excl + vals[i];
      off[idx] = o2;
      cur[idx] = o2;
    }
  }
  if (t == 255) off[NN] = excl + local;
}

__global__ void scatter_kernel(const int* __restrict__ dst, const int* __restrict__ src,
                               int* __restrict__ cur, int* __restrict__ eids, int* __restrict__ srcs) {
  int e = blockIdx.x * 256 + threadIdx.x;
  if (e < NE) {
    int p = atomicAdd(&cur[dst[e]], 1);
    eids[p] = e;
    srcs[p] = src[e];
  }
}

// ---------------- init: node_feats -> bf16 mirror + layer-0 BN stats ----------------
__global__ __launch_bounds__(256) void init_kernel(const float* __restrict__ hv,
                                                   u32x2* __restrict__ hvb,
                                                   float* __restrict__ statsN) {
  __shared__ float bsum[64], bsq[64];
  int n = blockIdx.x, t = threadIdx.x;
  if (t < 64) {
    bsum[t] = 0.f;
    bsq[t] = 0.f;
  }
  __syncthreads();
  const float4* hv4 = (const float4*)hv;
#pragma unroll
  for (int j = 0; j < 3; j++) {
    int q = t + j * 256;
    int c = q / 12;
    float4 v = hv4[(size_t)n * CHW4 + q];
    u32x2 o;
    o.x = pack_bf16(v.x, v.y);
    o.y = pack_bf16(v.z, v.w);
    hvb[(size_t)n * CHW4 + q] = o;
    atomicAdd(&bsum[c], v.x + v.y + v.z + v.w);
    atomicAdd(&bsq[c], v.x * v.x + v.y * v.y + v.z * v.z + v.w * v.w);
  }
  __syncthreads();
  int r = n & 7;
  if (t < 64) atomicAdd(&statsN[r * 128 + t], bsum[t]);
  else if (t < 128) atomicAdd(&statsN[r * 128 + 64 + (t - 64)], bsq[t - 64]);
}

__global__ void finalize2_kernel(const float* __restrict__ statsN, const float* __restrict__ gamma,
                                 const float* __restrict__ beta, float* __restrict__ sc,
                                 float* __restrict__ sh) {
  int c = threadIdx.x;
  if (c < C) {
    float s = 0.f, q = 0.f;
#pragma unroll
    for (int r = 0; r < 8; r++) {
      s += statsN[r * 128 + c];
      q += statsN[r * 128 + 64 + c];
    }
    const float inv = 1.f / 240000.f;
    float mu = s * inv;
    float var = q * inv - mu * mu;
    float scale = gamma[c] * rsqrtf(var + 1e-5f);
    sc[c] = scale;
    sh[c] = beta[c] - mu * scale;
  }
}

// ---------------- Fused GENConv layer ----------------
// One block per node. Gathers raw bf16 hv mirror + applies BN+ReLU inline;
// he streamed with nontemporal loads (L2 temporal hint only).
// Shift-free softmax (m bounded); 64x64 linear + residual + next BN stats.
template <bool FIRST, bool LAST>
__global__ __launch_bounds__(256) void aggregate_kernel(
    const float* __restrict__ hv, const float* __restrict__ he,
    const u32x2* __restrict__ hvbIn, u32x2* __restrict__ hvbOut,
    u32x2* __restrict__ heb,
    const int* __restrict__ srcs, const int* __restrict__ eids, const int* __restrict__ off,
    const float* __restrict__ Wg, const float* __restrict__ bg,
    const float* __restrict__ sc, const float* __restrict__ sh,
    float* __restrict__ hvNext, float* __restrict__ statsNext,
    const float* __restrict__ oW, const float* __restrict__ ob,
    float* __restrict__ out) {
  __shared__ float Wl[4096];
  __shared__ float fl[3072];
  __shared__ float scl[64], shl[64];
  __shared__ int sS[MAXD], sE[MAXD];
  __shared__ float bsum[64], bsq[64];

  int n = blockIdx.x, t = threadIdx.x;
  for (int i = t; i < 4096; i += 256) Wl[i] = Wg[i];
  if (t < 64) {
    scl[t] = sc[t];
    shl[t] = sh[t];
    bsum[t] = 0.f;
    bsq[t] = 0.f;
  }
  __syncthreads();

  const float4* hv4 = (const float4*)hv;
  const f32x4* heV = (const f32x4*)he;

  float scv[3], shv[3], h1[12];
#pragma unroll
  for (int j = 0; j < 3; j++) {
    int q = t + j * 256;
    int c = q / 12;
    scv[j] = scl[c];
    shv[j] = shl[c];
    float4 v = hv4[(size_t)n * CHW4 + q];
    h1[4 * j + 0] = fmaxf(v.x * scv[j] + shv[j], 0.f);
    h1[4 * j + 1] = fmaxf(v.y * scv[j] + shv[j], 0.f);
    h1[4 * j + 2] = fmaxf(v.z * scv[j] + shv[j], 0.f);
    h1[4 * j + 3] = fmaxf(v.w * scv[j] + shv[j], 0.f);
  }

  float S[12], T[12];
#pragma unroll
  for (int i = 0; i < 12; i++) {
    S[i] = 0.f;
    T[i] = 0.f;
  }

  int e0 = off[n], d = off[n + 1] - e0;
  for (int base = 0; base < d; base += MAXD) {
    int cnt = min(MAXD, d - base);
    __syncthreads();
    if (t < cnt) {
      sS[t] = srcs[e0 + base + t];
      if (FIRST) sE[t] = eids[e0 + base + t];
    }
    __syncthreads();
#pragma unroll 2
    for (int k = 0; k < cnt; k++) {
      size_t hb = (size_t)sS[k] * CHW4;
      size_t pbq = (size_t)(e0 + base + k) * CHW4;  // CSR-slot base for heb
#pragma unroll
      for (int j = 0; j < 3; j++) {
        int q = t + j * 256;
        u32x2 hg = hvbIn[hb + q];  // bf16 raw-hv gather (cacheable)
        float hgf[4];
        hgf[0] = fmaxf(bf_lo(hg.x) * scv[j] + shv[j], 0.f);
        hgf[1] = fmaxf(bf_hi(hg.x) * scv[j] + shv[j], 0.f);
        hgf[2] = fmaxf(bf_lo(hg.y) * scv[j] + shv[j], 0.f);
        hgf[3] = fmaxf(bf_hi(hg.y) * scv[j] + shv[j], 0.f);
        float hef[4];
        if (FIRST) {
          f32x4 b = __builtin_nontemporal_load(&heV[(size_t)sE[k] * CHW4 + q]);
          hef[0] = b.x; hef[1] = b.y; hef[2] = b.z; hef[3] = b.w;
          u32x2 o;
          o.x = pack_bf16(b.x, b.y);
          o.y = pack_bf16(b.z, b.w);
          __builtin_nontemporal_store(o, &heb[pbq + q]);
        } else {
          u32x2 bb = __builtin_nontemporal_load(&heb[pbq + q]);
          hef[0] = bf_lo(bb.x); hef[1] = bf_hi(bb.x); hef[2] = bf_lo(bb.y); hef[3] = bf_hi(bb.y);
        }
#pragma unroll
        for (int u = 0; u < 4; u++) {
          float m = fmaxf(hgf[u] + hef[u], 0.f) + 1e-7f;
          float e = __expf(m);  // shift-free softmax: m bounded, no overflow
          int idx = j * 4 + u;
          S[idx] += e;
          T[idx] += e * m;
        }
      }
    }
  }

  bool hasE = d > 0;
  float4* fl4 = (float4*)fl;
#pragma unroll
  for (int j = 0; j < 3; j++) {
    int q = t + j * 256, idx = 4 * j;
    float4 f;
    f.x = h1[idx + 0] + (hasE ? T[idx + 0] / S[idx + 0] : 0.f);
    f.y = h1[idx + 1] + (hasE ? T[idx + 1] / S[idx + 1] : 0.f);
    f.z = h1[idx + 2] + (hasE ? T[idx + 2] / S[idx + 2] : 0.f);
    f.w = h1[idx + 3] + (hasE ? T[idx + 3] / S[idx + 3] : 0.f);
    fl4[q] = f;
  }
  __syncthreads();

  // linear: 192 threads, each owns 4 consecutive out-channels x one h position
  int o0 = (t / 12) * 4, hbp = t % 12;
  float4 acc[4];
  if (t < 192) {
#pragma unroll
    for (int i = 0; i < 4; i++) {
      float bv = bg[o0 + i];
      acc[i] = make_float4(bv, bv, bv, bv);
    }
    const float4* w4 = (const float4*)Wl;
    int widx = o0 >> 2;
    for (int c2 = 0; c2 < 64; c2++) {
      float4 fv = fl4[c2 * 12 + hbp];
      float4 wv = w4[c2 * 16 + widx];
      acc[0].x += wv.x * fv.x; acc[0].y += wv.x * fv.y; acc[0].z += wv.x * fv.z; acc[0].w += wv.x * fv.w;
      acc[1].x += wv.y * fv.x; acc[1].y += wv.y * fv.y; acc[1].z += wv.y * fv.z; acc[1].w += wv.y * fv.w;
      acc[2].x += wv.z * fv.x; acc[2].y += wv.z * fv.y; acc[2].z += wv.z * fv.z; acc[2].w += wv.z * fv.w;
      acc[3].x += wv.w * fv.x; acc[3].y += wv.w * fv.y; acc[3].z += wv.w * fv.z; acc[3].w += wv.w * fv.w;
    }
#pragma unroll
    for (int i = 0; i < 4; i++) {
      float4 r = hv4[(size_t)n * CHW4 + (o0 + i) * 12 + hbp];
      acc[i].x += r.x; acc[i].y += r.y; acc[i].z += r.z; acc[i].w += r.w;
    }
  }

  if constexpr (!LAST) {
    if (t < 192) {
      float4* hn4 = (float4*)hvNext;
#pragma unroll
      for (int i = 0; i < 4; i++) {
        int pos = (o0 + i) * 12 + hbp;
        hn4[(size_t)n * CHW4 + pos] = acc[i];
        u32x2 ob2;
        ob2.x = pack_bf16(acc[i].x, acc[i].y);
        ob2.y = pack_bf16(acc[i].z, acc[i].w);
        hvbOut[(size_t)n * CHW4 + pos] = ob2;  // bf16 mirror for next layer's gathers
        float s4 = acc[i].x + acc[i].y + acc[i].z + acc[i].w;
        float q4 = acc[i].x * acc[i].x + acc[i].y * acc[i].y + acc[i].z * acc[i].z + acc[i].w * acc[i].w;
        atomicAdd(&bsum[o0 + i], s4);
        atomicAdd(&bsq[o0 + i], q4);
      }
    }
    __syncthreads();
    int r = n & 7;
    if (t < 64) atomicAdd(&statsNext[r * 128 + t], bsum[t]);
    else if (t < 128) atomicAdd(&statsNext[r * 128 + 64 + (t - 64)], bsq[t - 64]);
  } else {
    __syncthreads();
    if (t < 192) {
#pragma unroll
      for (int i = 0; i < 4; i++) fl4[(o0 + i) * 12 + hbp] = acc[i];
    }
    for (int i = t; i < 768; i += 256) Wl[i] = oW[i];
    __syncthreads();
    for (int i = t; i < 768; i += 256) {
      float4 v = fl4[i];
      Wl[1024 + i] = (v.x + v.y + v.z + v.w) * 0.25f;
    }
    __syncthreads();
    if (t < 144) {
      int o = t / 12, hb = t % 12;
      float bias = ob[o];
      float4 a = make_float4(bias, bias, bias, bias);
      for (int c2 = 0; c2 < 64; c2++) {
        float4 v = fl4[c2 * 12 + hb];
        float wv = Wl[c2 * 12 + o] * Wl[1024 + c2 * 12 + hb];
        a.x += wv * v.x; a.y += wv * v.y; a.z += wv * v.z; a.w += wv * v.w;
      }
      ((float4*)out)[(size_t)n * 144 + t] = a;
    }
  }
}

extern "C" void kernel_launch(void* const* d_in, const int* in_sizes, int n_in,
                              void* d_out, int out_size, void* d_ws, size_t ws_size,
                              hipStream_t stream) {
  const float* node_feats = (const float*)d_in[0];
  const float* edge_feats = (const float*)d_in[1];
  const int* src = (const int*)d_in[2];
  const int* dst = (const int*)d_in[3];
  const float* bn_gamma = (const float*)d_in[4];
  const float* bn_beta = (const float*)d_in[5];
  const float* gen_W = (const float*)d_in[6];
  const float* gen_b = (const float*)d_in[7];
  const float* out_W = (const float*)d_in[8];
  const float* out_b = (const float*)d_in[9];
  float* out = (float*)d_out;

  char* ws = (char*)d_ws;
  float* hvA = (float*)ws;                        // 61,440,000 B
  float* hvB = (float*)(ws + 61440000);           // 61,440,000 B
  u32x2* hvbA = (u32x2*)(ws + 122880000);         // 30,720,000 B (bf16 raw hv)
  u32x2* hvbB = (u32x2*)(ws + 153600000);         // 30,720,000 B
  u32x2* heb = (u32x2*)(ws + 184320000);          // 307,200,000 B (bf16 he, CSR order)
  float* statsN = (float*)(ws + 491520000);       // 4096 B
  float* sc = (float*)(ws + 491524096);           // 256 B
  float* sh = (float*)(ws + 491524352);           // 256 B
  int* cnt = (int*)(ws + 491524608);              // 20,000 B
  int* off = (int*)(ws + 491544608);              // 20,004 B
  int* cur = (int*)(ws + 491564612);              // 20,000 B
  int* eids = (int*)(ws + 491584612);             // 200,000 B
  int* srcs = (int*)(ws + 491784612);             // 200,000 B

  hipMemsetAsync(cnt, 0, NN * sizeof(int), stream);
  hist_kernel<<<(NE + 255) / 256, 256, 0, stream>>>(dst, cnt);
  scan_kernel<<<1, 256, 0, stream>>>(cnt, off, cur);
  scatter_kernel<<<(NE + 255) / 256, 256, 0, stream>>>(dst, src, cur, eids, srcs);

  hipMemsetAsync(statsN, 0, 1024 * sizeof(float), stream);
  init_kernel<<<NN, 256, 0, stream>>>(node_feats, hvbA, statsN);

  // layer 0
  finalize2_kernel<<<1, 64, 0, stream>>>(statsN, bn_gamma, bn_beta, sc, sh);
  hipMemsetAsync(statsN, 0, 1024 * sizeof(float), stream);
  aggregate_kernel<true, false><<<NN, 256, 0, stream>>>(
      node_feats, edge_feats, hvbA, hvbB, heb, srcs, eids, off, gen_W, gen_b,
      sc, sh, hvA, statsN, out_W, out_b, out);

  // layer 1
  finalize2_kernel<<<1, 64, 0, stream>>>(statsN, bn_gamma + C, bn_beta + C, sc, sh);
  hipMemsetAsync(statsN, 0, 1024 * sizeof(float), stream);
  aggregate_kernel<false, false><<<NN, 256, 0, stream>>>(
      hvA, edge_feats, hvbB, hvbA, heb, srcs, eids, off, gen_W + C * C, gen_b + C,
      sc, sh, hvB, statsN, out_W, out_b, out);

  // layer 2 (fused output)
  finalize2_kernel<<<1, 64, 0, stream>>>(statsN, bn_gamma + 2 * C, bn_beta + 2 * C, sc, sh);
  aggregate_kernel<false, true><<<NN, 256, 0, stream>>>(
      hvB, edge_feats, hvbA, hvbB, heb, srcs, eids, off, gen_W + 2 * C * C, gen_b + 2 * C,
      sc, sh, hvA, statsN, out_W, out_b, out);
}